// Round 5
// baseline (714.413 us; speedup 1.0000x reference)
//
#include <hip/hip_runtime.h>
#include <stdint.h>

#define T_LEN 2048
#define N_TAG 128

typedef __attribute__((ext_vector_type(4))) float f32x4;
typedef __attribute__((ext_vector_type(8))) short bf16x8;
typedef __attribute__((ext_vector_type(4))) uint32_t u32x4;

template <int S>
struct IC {
  static constexpr int value = S;
};

// pack two fp32 -> dword of two bf16 (round-half-up); elem0 in low half
__device__ __forceinline__ uint32_t pack2_bf16(float a, float b) {
  uint32_t ua = __float_as_uint(a) + 0x8000u;
  uint32_t ub = __float_as_uint(b) + 0x8000u;
  return __builtin_amdgcn_perm(ua, ub, 0x03020706u);
}

// Workgroup barrier that drains ONLY lgkmcnt (LDS), NOT vmcnt -- keeps the
// global em prefetch in flight across the barrier. __syncthreads() would
// emit s_waitcnt vmcnt(0) and expose full HBM latency on every step.
__device__ __forceinline__ void barrier_lds_only() {
  __asm__ volatile("s_waitcnt lgkmcnt(0)\n\ts_barrier" ::: "memory");
}

// 16 batches/block, 4 waves/block (j-split: wave w owns j in [32w,32w+32)),
// 4 blocks. A-operand rows are PERMUTED (j = 32w + (m>>2)*8 + tl*4 + (m&3))
// so MFMA D output lands directly in next step's B-fragment layout -- the
// state never leaves registers except a 1-write/3-read fragment exchange.
// exp(em) fused. Rescale: j=0 exponent probe, deferred 1 step.
__global__ __launch_bounds__(256, 1) void crf_fwd_kernel(
    const float* __restrict__ em, const int* __restrict__ lens,
    const float* __restrict__ trans, const float* __restrict__ head,
    const float* __restrict__ last, float* __restrict__ out) {
  const int lane = threadIdx.x & 63;
  const int w = threadIdx.x >> 6;  // wave id
  const int c = lane & 15;         // batch-in-tile
  const int q = lane >> 4;
  const int bg = (int)blockIdx.x * 16 + c;

  __shared__ u32x4 x_lds[2][4][64];  // [pingpong][frag u][lane]
  __shared__ int k_lds[16];
  __shared__ float cap_lds[4][16];

  // E^T fragments (A operand), row-permuted; virtual kt: phys = (w+ktv)&3
  bf16x8 efrag[2][4];
#pragma unroll
  for (int tl = 0; tl < 2; ++tl) {
    const int j = w * 32 + (c >> 2) * 8 + tl * 4 + (c & 3);
#pragma unroll
    for (int ktv = 0; ktv < 4; ++ktv) {
      const int ktp = (w + ktv) & 3;
      u32x4 wd;
#pragma unroll
      for (int p = 0; p < 4; ++p) {
        const int i0 = ktp * 32 + q * 8 + 2 * p;
        wd[p] = pack2_bf16(__expf(trans[(i0 + 0) * N_TAG + j]),
                           __expf(trans[(i0 + 1) * N_TAG + j]));
      }
      efrag[tl][ktv] = __builtin_bit_cast(bf16x8, wd);
    }
  }

  float lastx[8];
#pragma unroll
  for (int jj = 0; jj < 8; ++jj) lastx[jj] = __expf(last[w * 32 + q * 8 + jj]);

  const int len = lens[bg];
  float L = 0.f, Lcap = 0.f;

  // initial state frag u=w: i = 32w + q*8 + jj
  const float* emb = em + (size_t)bg * T_LEN * N_TAG;
  float v0[8];
#pragma unroll
  for (int jj = 0; jj < 8; ++jj) {
    const int i = w * 32 + q * 8 + jj;
    v0[jj] = __expf(head[i] + emb[i]);
  }
  u32x4 bloc;
#pragma unroll
  for (int p = 0; p < 4; ++p) bloc[p] = pack2_bf16(v0[2 * p], v0[2 * p + 1]);
  x_lds[0][w][lane] = bloc;
  if (threadIdx.x < 16) k_lds[threadIdx.x] = 0;

  if (len == 1) {  // edge case (setup guarantees len>=1024, keep correct)
    float s = 0.f;
#pragma unroll
    for (int jj = 0; jj < 8; ++jj) s += v0[jj] * lastx[jj];
    s += __shfl_xor(s, 16);
    s += __shfl_xor(s, 32);
    if (q == 0) cap_lds[w][c] = s;
  }
  __syncthreads();
  if (len == 1 && threadIdx.x < 16)
    out[bg] =
        __logf(cap_lds[0][c] + cap_lds[1][c] + cap_lds[2][c] + cap_lds[3][c]);

  // em prefetch: slot t&3 holds raw em row t (this wave's 8 j's)
  float4 embuf[4][2];
  auto issue_em = [&](int row, int slot) {
    const float4* p =
        (const float4*)(emb + (size_t)row * N_TAG + w * 32 + q * 8);
    embuf[slot][0] = p[0];
    embuf[slot][1] = p[1];
  };
  issue_em(1, 1);
  issue_em(2, 2);
  issue_em(3, 3);

  const f32x4 vzero = {0.f, 0.f, 0.f, 0.f};

  auto step = [&](auto slotc, int t) {
    constexpr int SLOT = decltype(slotc)::value;
    constexpr int RP = (SLOT + 1) & 1;  // read buffer (state of t-1)
    constexpr int WP = SLOT & 1;        // write buffer
    // prefetch em row t+3 first (VMEM issue before any LDS dependency)
    {
      int row = t + 3;
      if (row > T_LEN - 1) row = T_LEN - 1;
      issue_em(row, (SLOT + 3) & 3);
    }
    int e = 0;
    if (SLOT == 1) e = k_lds[c];
    // remote fragment reads -- issue immediately after barrier
    const u32x4 bf1 = x_lds[RP][(w + 1) & 3][lane];
    const u32x4 bf2 = x_lds[RP][(w + 2) & 3][lane];
    const u32x4 bf3 = x_lds[RP][(w + 3) & 3][lane];
    // eem = exp(em_t) -- no LDS dependency, fills the read-latency bubble
    float eemf[8];
    eemf[0] = __expf(embuf[SLOT][0].x);
    eemf[1] = __expf(embuf[SLOT][0].y);
    eemf[2] = __expf(embuf[SLOT][0].z);
    eemf[3] = __expf(embuf[SLOT][0].w);
    eemf[4] = __expf(embuf[SLOT][1].x);
    eemf[5] = __expf(embuf[SLOT][1].y);
    eemf[6] = __expf(embuf[SLOT][1].z);
    eemf[7] = __expf(embuf[SLOT][1].w);
    if (SLOT == 1) {
      // fold 2^-e into eem; L updated BEFORE capture => identical output
      const float sc = __uint_as_float((uint32_t)(127 - e) << 23);
#pragma unroll
      for (int jj = 0; jj < 8; ++jj) eemf[jj] *= sc;
      L += (float)e * 0.6931471805599453f;
    }
    // MFMA: local frag first (no read dependency), two 2-deep chains
    f32x4 a0 = __builtin_amdgcn_mfma_f32_16x16x32_bf16(
        efrag[0][0], __builtin_bit_cast(bf16x8, bloc), vzero, 0, 0, 0);
    f32x4 a1 = __builtin_amdgcn_mfma_f32_16x16x32_bf16(
        efrag[1][0], __builtin_bit_cast(bf16x8, bloc), vzero, 0, 0, 0);
    f32x4 b0 = __builtin_amdgcn_mfma_f32_16x16x32_bf16(
        efrag[0][1], __builtin_bit_cast(bf16x8, bf1), vzero, 0, 0, 0);
    f32x4 b1 = __builtin_amdgcn_mfma_f32_16x16x32_bf16(
        efrag[1][1], __builtin_bit_cast(bf16x8, bf1), vzero, 0, 0, 0);
    a0 = __builtin_amdgcn_mfma_f32_16x16x32_bf16(
        efrag[0][2], __builtin_bit_cast(bf16x8, bf2), a0, 0, 0, 0);
    a1 = __builtin_amdgcn_mfma_f32_16x16x32_bf16(
        efrag[1][2], __builtin_bit_cast(bf16x8, bf2), a1, 0, 0, 0);
    b0 = __builtin_amdgcn_mfma_f32_16x16x32_bf16(
        efrag[0][3], __builtin_bit_cast(bf16x8, bf3), b0, 0, 0, 0);
    b1 = __builtin_amdgcn_mfma_f32_16x16x32_bf16(
        efrag[1][3], __builtin_bit_cast(bf16x8, bf3), b1, 0, 0, 0);
    const f32x4 acc0 = a0 + b0;
    const f32x4 acc1 = a1 + b1;
    // capture: out_b = log(sum_j acc*eem*e^{last}) + L  (this wave's 8 j's)
    if (t == len - 1) {
      float s = acc0[0] * eemf[0] * lastx[0] + acc0[1] * eemf[1] * lastx[1] +
                acc0[2] * eemf[2] * lastx[2] + acc0[3] * eemf[3] * lastx[3] +
                acc1[0] * eemf[4] * lastx[4] + acc1[1] * eemf[5] * lastx[5] +
                acc1[2] * eemf[6] * lastx[6] + acc1[3] * eemf[7] * lastx[7];
      s += __shfl_xor(s, 16);
      s += __shfl_xor(s, 32);
      if (q == 0) cap_lds[w][c] = s;
      Lcap = L;
    }
    if (SLOT == 0) {
      // exponent probe of j=0 (wave 0, q==0 lanes): acc0[0] = alpha[j=0][c]
      if (threadIdx.x < 16)
        k_lds[c] = (int)(__float_as_uint(acc0[0]) >> 23) - 126;
    }
    // pack next state frag (already in B-fragment layout -- lane-local)
    u32x4 wd;
    wd[0] = pack2_bf16(acc0[0] * eemf[0], acc0[1] * eemf[1]);
    wd[1] = pack2_bf16(acc0[2] * eemf[2], acc0[3] * eemf[3]);
    wd[2] = pack2_bf16(acc1[0] * eemf[4], acc1[1] * eemf[5]);
    wd[3] = pack2_bf16(acc1[2] * eemf[6], acc1[3] * eemf[7]);
    bloc = wd;
    x_lds[WP][w][lane] = wd;
    barrier_lds_only();  // LDS-ordered barrier; vmem prefetch stays in flight
    if (t == len - 1 && threadIdx.x < 16)
      out[bg] =
          __logf(cap_lds[0][c] + cap_lds[1][c] + cap_lds[2][c] + cap_lds[3][c]) +
          Lcap;
  };

  int t = 1;
#pragma unroll 1
  for (int it = 0; it < 511; ++it) {  // t = 1 .. 2044
    step(IC<1>{}, t);
    step(IC<2>{}, t + 1);
    step(IC<3>{}, t + 2);
    step(IC<0>{}, t + 3);
    t += 4;
  }
  step(IC<1>{}, t);      // 2045
  step(IC<2>{}, t + 1);  // 2046
  step(IC<3>{}, t + 2);  // 2047
}

extern "C" void kernel_launch(void* const* d_in, const int* in_sizes, int n_in,
                              void* d_out, int out_size, void* d_ws,
                              size_t ws_size, hipStream_t stream) {
  const float* em = (const float*)d_in[0];
  const int* lens = (const int*)d_in[1];
  const float* trans = (const float*)d_in[2];
  const float* head = (const float*)d_in[3];
  const float* last = (const float*)d_in[4];
  float* out = (float*)d_out;
  crf_fwd_kernel<<<4, 256, 0, stream>>>(em, lens, trans, head, last, out);
}